// Round 10
// baseline (92.354 us; speedup 1.0000x reference)
//
#include <hip/hip_runtime.h>
#include <hip/hip_fp16.h>

typedef _Float16 half8 __attribute__((ext_vector_type(8)));
typedef _Float16 half4v __attribute__((ext_vector_type(4)));
typedef _Float16 half2v __attribute__((ext_vector_type(2)));
typedef float f32x4 __attribute__((ext_vector_type(4)));

#define N_INNER 511
#define NPAD 512
#define FEAT 1024
#define BATCH 16384
#define NCLS 100
#define NCLSPAD 112

#define AS1 __attribute__((address_space(1)))
#define AS3 __attribute__((address_space(3)))

// ---------------- prep: W -> Wh f16 [512][1024] (row 511 zero); L -> LT f16 [112][512] ----------------
__global__ void k_prep(const float* __restrict__ W, const float* __restrict__ L,
                       _Float16* __restrict__ Wh, _Float16* __restrict__ LT) {
  const int i = blockIdx.x * 256 + threadIdx.x;

  if (i < 65536) {
    const int off = i * 8;
    const int row = off >> 10;
    half8 h;
    if (row < N_INNER) {
      const f32x4 a = *(const f32x4*)(W + off);
      const f32x4 b = *(const f32x4*)(W + off + 4);
      h[0] = (_Float16)a[0]; h[1] = (_Float16)a[1]; h[2] = (_Float16)a[2]; h[3] = (_Float16)a[3];
      h[4] = (_Float16)b[0]; h[5] = (_Float16)b[1]; h[6] = (_Float16)b[2]; h[7] = (_Float16)b[3];
    } else {
      h = (half8)(_Float16)0.f;
    }
    *(half8*)(Wh + off) = h;
  }

  if (i < NCLSPAD * NPAD) {
    const int n = i >> 9, k = i & 511;
    LT[i] = (n < NCLS) ? (_Float16)L[(size_t)k * NCLS + n] : (_Float16)0.f;
  }
}

// ---------------- GEMM1 (weight-stationary): gates = sigmoid(x @ Wh^T + b) ----------------
// Grid 256 = 8 bn x 32 bm-groups; all 8 bn-siblings of a bm-group on ONE XCD (x shared via L2).
// Block: Wh rows [bn*64, +64) XOR-chunk-swizzled in LDS (128 KB), loaded ONCE.
// Streams 512 x-rows in 8 m-steps x 16 k-steps (BK=64); A f32->f16 reg-staged, 2-ahead ping-pong.
// No global_load_lds in main loop; raw barrier (lgkmcnt(0) only, never vmcnt(0) drain).
#define LDAR 72  // A LDS row stride (f16): 144 B, 16B-aligned frag reads

#define BARX do { asm volatile("s_waitcnt lgkmcnt(0)" ::: "memory"); \
                  __builtin_amdgcn_s_barrier();                      \
                  __builtin_amdgcn_sched_barrier(0); } while (0)

__global__ __launch_bounds__(512, 1) void k_gemm1(
    const float* __restrict__ x, const _Float16* __restrict__ Wh,
    const float* __restrict__ bias, _Float16* __restrict__ gates) {
  __shared__ _Float16 lB[64 * 1024];     // 128 KB, chunk c of row n stored at c ^ (n&7)
  __shared__ _Float16 lA[2][64 * LDAR];  // 18 KB dbuf

  const int t = threadIdx.x;
  const int lane = t & 63;
  const int w = t >> 6;

  const int bid = blockIdx.x;
  const int bn = (bid >> 3) & 7;                      // 0..7
  const int bmg = (bid & 7) | ((bid >> 6) << 3);      // 0..31 ; xcd = bid&7 = bmg&7

  // ---- B fill (once): 16 calls x 512 threads x 16B. dest byte = c*8192 + t*16 (linear).
  //      dest (row, chunk c') with row = c*4 + (t>>7), c' = t&127; source chunk = c' ^ (row&7).
  {
    const int cp = t & 127;
#pragma unroll
    for (int c = 0; c < 16; ++c) {
      const int row = c * 4 + (t >> 7);
      const _Float16* src = Wh + ((size_t)(bn * 64 + row)) * FEAT + (cp ^ (row & 7)) * 8;
      __builtin_amdgcn_global_load_lds((const AS1 void*)src,
                                       (AS3 void*)((char*)lB + c * 8192 + w * 1024), 16, 0, 0);
    }
  }

  // ---- A staging map: thread t owns (row t>>3, f32x4 segs t&7 and 8+(t&7)) of a 64x64 f32 step
  const float* paw = x + ((size_t)bmg * 512 + (t >> 3)) * FEAT + (t & 7) * 4;
  const int aoff = (t >> 3) * LDAR + (t & 7) * 4;

  const int mf = w >> 1, nfb = (w & 1) * 2;
  const int arow = mf * 16 + (lane & 15);
  const int g4 = lane >> 4;

  f32x4 acc[2] = {};
  f32x4 e0a, e0b, e1a, e1b;

  auto aload = [&](int s, f32x4& u, f32x4& v) {
    const float* p = paw + (size_t)(s >> 4) * (64 * FEAT) + (s & 15) * 64;
    u = *(const f32x4*)p;
    v = *(const f32x4*)(p + 32);
  };
  auto awrite = [&](int buf, const f32x4& u, const f32x4& v) {
    half4v h0, h1;
    h0[0] = (_Float16)u[0]; h0[1] = (_Float16)u[1]; h0[2] = (_Float16)u[2]; h0[3] = (_Float16)u[3];
    h1[0] = (_Float16)v[0]; h1[1] = (_Float16)v[1]; h1[2] = (_Float16)v[2]; h1[3] = (_Float16)v[3];
    *(half4v*)&lA[buf][aoff] = h0;
    *(half4v*)&lA[buf][aoff + 32] = h1;
  };
  auto comp = [&](int kk, const _Float16* la) {
    const half8 af0 = *(const half8*)&la[arow * LDAR + g4 * 8];
    const half8 af1 = *(const half8*)&la[arow * LDAR + 32 + g4 * 8];
#pragma unroll
    for (int j = 0; j < 2; ++j) {
      const int n = (nfb + j) * 16 + (lane & 15);
      const int q0 = kk * 8 + g4, q1 = kk * 8 + 4 + g4;
      const half8 bf0 = *(const half8*)&lB[n * 1024 + (q0 ^ (n & 7)) * 8];
      const half8 bf1 = *(const half8*)&lB[n * 1024 + (q1 ^ (n & 7)) * 8];
      acc[j] = __builtin_amdgcn_mfma_f32_16x16x32_f16(af0, bf0, acc[j], 0, 0, 0);
      acc[j] = __builtin_amdgcn_mfma_f32_16x16x32_f16(af1, bf1, acc[j], 0, 0, 0);
    }
  };
  auto epilogue = [&](int ms) {
#pragma unroll
    for (int j = 0; j < 2; ++j) {
      const int col = bn * 64 + (nfb + j) * 16 + (lane & 15);
      const float bb = (col < N_INNER) ? bias[col] : 0.f;
      const int hpos = (col + 1) & 511;
      const int rowb = bmg * 512 + ms * 64 + mf * 16 + g4 * 4;
#pragma unroll
      for (int r = 0; r < 4; ++r) {
        float v = acc[j][r] + bb;
        v = 1.f / (1.f + __expf(-v));
        gates[(size_t)(rowb + r) * NPAD + hpos] = (_Float16)v;
      }
      acc[j] = (f32x4){0.f, 0.f, 0.f, 0.f};
    }
  };

  // prologue: A(0), A(1) in flight; wait B-fill(16) + A(0) done (vmcnt leaves A(1)'s 2 loads)
  aload(0, e0a, e0b);
  aload(1, e1a, e1b);
  asm volatile("s_waitcnt vmcnt(2)" ::: "memory");
  awrite(0, e0a, e0b);
  BARX;

#pragma unroll 1
  for (int sp = 0; sp < 64; ++sp) {
    const int s0 = sp * 2;
    if (s0 < 126) aload(s0 + 2, e0a, e0b);   // -> arrives for step s0+2 (buf 0)
    comp(s0 & 15, lA[0]);
    awrite(1, e1a, e1b);                      // data for s0+1
    BARX;

    const int s1 = s0 + 1;
    if (s1 < 126) aload(s1 + 2, e1a, e1b);
    comp(s1 & 15, lA[1]);
    if (s1 < 127) awrite(0, e0a, e0b);        // data for s1+1
    BARX;
    if ((s1 & 15) == 15) epilogue(s1 >> 4);
  }
}

// ---------------- K2: tree expansion + GEMM2 (prob @ leaf_logits) ----------------
#define LPS 520

__global__ __launch_bounds__(512, 4) void k_tree(
    const _Float16* __restrict__ gates, const _Float16* __restrict__ LT,
    float* __restrict__ out) {
  __shared__ _Float16 lp[32 * LPS];

  const int t = threadIdx.x;
  const int rowl = t >> 4, sub = t & 15;
  const size_t grow = (size_t)blockIdx.x * 32 + rowl;
  const _Float16* g = gates + grow * NPAD;

  const float f0 = (float)g[1];
  const float f1 = (float)g[2 + (sub >> 3)];
  const float f2 = (float)g[4 + (sub >> 2)];
  const float f3 = (float)g[8 + (sub >> 1)];
  const _Float16 g4 = g[16 + sub];
  const half2v g5 = *(const half2v*)(g + 32 + 2 * sub);
  const half4v g6 = *(const half4v*)(g + 64 + 4 * sub);
  const half8 g7 = *(const half8*)(g + 128 + 8 * sub);
  const half8 g8a = *(const half8*)(g + 256 + 16 * sub);
  const half8 g8b = *(const half8*)(g + 256 + 16 * sub + 8);

  float p = ((sub & 8) ? f0 : 1.f - f0) * ((sub & 4) ? f1 : 1.f - f1) *
            ((sub & 2) ? f2 : 1.f - f2) * ((sub & 1) ? f3 : 1.f - f3);

  float arr[32];
  {
    const float gg = (float)g4;
    arr[1] = p * gg; arr[0] = p - p * gg;
  }
#pragma unroll
  for (int i = 1; i >= 0; --i) {
    const float gg = (float)g5[i];
    const float pp = arr[i];
    arr[2 * i + 1] = pp * gg; arr[2 * i] = pp - pp * gg;
  }
#pragma unroll
  for (int i = 3; i >= 0; --i) {
    const float gg = (float)g6[i];
    const float pp = arr[i];
    arr[2 * i + 1] = pp * gg; arr[2 * i] = pp - pp * gg;
  }
#pragma unroll
  for (int i = 7; i >= 0; --i) {
    const float gg = (float)g7[i];
    const float pp = arr[i];
    arr[2 * i + 1] = pp * gg; arr[2 * i] = pp - pp * gg;
  }
#pragma unroll
  for (int i = 15; i >= 0; --i) {
    const float gg = (i < 8) ? (float)g8a[i] : (float)g8b[i - 8];
    const float pp = arr[i];
    arr[2 * i + 1] = pp * gg; arr[2 * i] = pp - pp * gg;
  }

  const int lb = sub * 32;
#pragma unroll
  for (int i = 0; i < 32; i += 8) {
    half8 h;
#pragma unroll
    for (int jj = 0; jj < 8; ++jj) h[jj] = (_Float16)arr[i + jj];
    *(half8*)&lp[rowl * LPS + lb + i] = h;
  }
  __syncthreads();

  const int lane = t & 63, w = t >> 6;
  if (w < 7) {
    f32x4 acc[2] = {};
#pragma unroll
    for (int k0 = 0; k0 < 512; k0 += 32) {
      const int n = w * 16 + (lane & 15);
      const half8 b8 = *(const half8*)&LT[(size_t)n * NPAD + k0 + (lane >> 4) * 8];
#pragma unroll
      for (int mf = 0; mf < 2; ++mf) {
        const half8 a = *(const half8*)&lp[(mf * 16 + (lane & 15)) * LPS + k0 + (lane >> 4) * 8];
        acc[mf] = __builtin_amdgcn_mfma_f32_16x16x32_f16(a, b8, acc[mf], 0, 0, 0);
      }
    }

    const int col = w * 16 + (lane & 15);
    if (col < NCLS) {
#pragma unroll
      for (int mf = 0; mf < 2; ++mf) {
        const int rowb = blockIdx.x * 32 + mf * 16 + ((lane >> 4) << 2);
#pragma unroll
        for (int r = 0; r < 4; ++r)
          out[(size_t)(rowb + r) * NCLS + col] = acc[mf][r];
      }
    }
  }
}

extern "C" void kernel_launch(void* const* d_in, const int* in_sizes, int n_in,
                              void* d_out, int out_size, void* d_ws, size_t ws_size,
                              hipStream_t stream) {
  const float* x = (const float*)d_in[0];
  const float* W = (const float*)d_in[1];
  const float* b = (const float*)d_in[2];
  const float* L = (const float*)d_in[3];
  float* out = (float*)d_out;

  char* ws = (char*)d_ws;
  _Float16* Wh    = (_Float16*)ws;                 // 1 MB @ 0
  _Float16* LT    = (_Float16*)(ws + (1u << 20));  // 112 KB @ 1 MB
  _Float16* gates = (_Float16*)(ws + (2u << 20));  // 16 MB @ 2 MB

  k_prep<<<256, 256, 0, stream>>>(W, L, Wh, LT);
  k_gemm1<<<256, 512, 0, stream>>>(x, Wh, b, gates);
  k_tree<<<512, 512, 0, stream>>>(gates, LT, out);
}